// Round 1
// baseline (1741.833 us; speedup 1.0000x reference)
//
#include <hip/hip_runtime.h>
#include <hip/hip_bf16.h>
#include <math.h>

#define B_ 4
#define N_ 2048
#define F_ 128
#define H_ 4
#define DIN 385
#define NEG_BIG_F -9.0e15f

__device__ __forceinline__ float gelu_f(float x){
  return 0.5f*x*(1.0f+erff(x*0.70710678118654752f));
}
__device__ __forceinline__ float sigmoid_f(float x){
  return 1.0f/(1.0f+expf(-x));
}

// ---------------- Kernel 1: per-token feature MLP -> h (B,N,F) ----------------
__global__ void __launch_bounds__(128) mlp_kernel(
    const float* __restrict__ deltas, const float* __restrict__ evt,
    const float* __restrict__ mw1, const float* __restrict__ mb1,
    const float* __restrict__ mw2, const float* __restrict__ mb2,
    const float* __restrict__ mw3, const float* __restrict__ mb3,
    const float* __restrict__ gw1, const float* __restrict__ gb1,
    const float* __restrict__ gw2, const float* __restrict__ gb2,
    float* __restrict__ h_out)
{
  int bn = blockIdx.x;
  int t  = threadIdx.x;
  __shared__ float comb[DIN];
  __shared__ float m1[F_];
  __shared__ float m2s[F_];
  __shared__ float g1[64];
  if (t==0) comb[0] = deltas[bn];
  for (int k=t;k<384;k+=128) comb[1+k] = evt[(size_t)bn*384+k];
  __syncthreads();
  float a1 = mb1[t];
  for (int k=0;k<DIN;k++) a1 += comb[k]*mw1[k*F_+t];
  float g1v = 0.f;
  if (t<64){
    g1v = gb1[t];
    for (int k=0;k<DIN;k++) g1v += comb[k]*gw1[k*64+t];
  }
  m1[t] = gelu_f(a1);
  if (t<64) g1[t] = gelu_f(g1v);
  __syncthreads();
  float a2 = mb2[t];
  for (int k=0;k<F_;k++) a2 += m1[k]*mw2[k*F_+t];
  m2s[t] = gelu_f(a2);
  __syncthreads();
  float a3 = mb3[t];
  for (int k=0;k<F_;k++) a3 += m2s[k]*mw3[k*F_+t];
  float ag = gb2[t];
  for (int k=0;k<64;k++) ag += g1[k]*gw2[k*F_+t];
  h_out[(size_t)bn*F_+t] = a3 * sigmoid_f(ag);
}

// ---------------- Kernel 2: Wh = h @ Wg[l,h]  plus s,t dot products ----------------
__global__ void __launch_bounds__(128) wh_kernel(
    const float* __restrict__ h,
    const float* __restrict__ Wg_l,
    const float* __restrict__ asrc_l,
    const float* __restrict__ adst_l,
    float* __restrict__ Wh,
    float* __restrict__ sArr,
    float* __restrict__ tArr)
{
  int bn = blockIdx.x;
  int t = threadIdx.x;
  int b = bn >> 11, n = bn & (N_-1);
  __shared__ float hrow[F_];
  __shared__ float reds[2], redt[2];
  hrow[t] = h[(size_t)bn*F_+t];
  __syncthreads();
  for (int hh=0; hh<H_; hh++){
    const float* W = Wg_l + hh*F_*F_;
    float acc = 0.f;
    for (int k=0;k<F_;k++) acc += hrow[k]*W[k*F_+t];
    size_t idx = ((size_t)(b*H_+hh)*N_ + n);
    Wh[idx*F_ + t] = acc;
    float sv = acc * asrc_l[hh*F_+t];
    float tv = acc * adst_l[hh*F_+t];
    #pragma unroll
    for (int off=32; off>0; off>>=1){
      sv += __shfl_down(sv, off);
      tv += __shfl_down(tv, off);
    }
    if ((t&63)==0){ reds[t>>6]=sv; redt[t>>6]=tv; }
    __syncthreads();
    if (t==0){
      sArr[idx] = reds[0]+reds[1];
      tArr[idx] = redt[0]+redt[1];
    }
    __syncthreads();
  }
}

// ---------------- Kernel 3: masked softmax + sparse PV + pw projection ----------------
__global__ void __launch_bounds__(128) attn_kernel(
    const float* __restrict__ adj,
    const float* __restrict__ Wh,
    const float* __restrict__ sArr,
    const float* __restrict__ tArr,
    const float* __restrict__ pw_l,
    const float* __restrict__ pb_l,
    float* __restrict__ h_out)
{
  int bn = blockIdx.x;
  int t = threadIdx.x;
  int b = bn >> 11, n = bn & (N_-1);
  __shared__ float adjL[N_];
  __shared__ float pbuf[H_][128];
  __shared__ float red[H_][2];
  __shared__ float hpL[H_*F_];
  const float* arow = adj + (size_t)bn*N_;
  for (int j=t;j<N_;j+=128) adjL[j] = arow[j];
  float sh[H_];
  const float* tbase = tArr + (size_t)b*H_*N_;
  #pragma unroll
  for (int hh=0;hh<H_;hh++) sh[hh] = sArr[(size_t)(b*H_+hh)*N_ + n];
  __syncthreads();

  // pass 1: per-head row max (masked entries are NEG_BIG)
  float mx[H_];
  #pragma unroll
  for (int hh=0;hh<H_;hh++) mx[hh] = NEG_BIG_F;
  for (int j=t;j<N_;j+=128){
    if (adjL[j] > 0.f){
      #pragma unroll
      for (int hh=0;hh<H_;hh++){
        float e = sh[hh] + tbase[hh*N_+j];
        e = (e>0.f)? e : 0.2f*e;
        mx[hh] = fmaxf(mx[hh], e);
      }
    }
  }
  #pragma unroll
  for (int hh=0;hh<H_;hh++){
    float v = mx[hh];
    #pragma unroll
    for (int off=32; off>0; off>>=1) v = fmaxf(v, __shfl_down(v, off));
    if ((t&63)==0) red[hh][t>>6]=v;
  }
  __syncthreads();
  float m[H_];
  #pragma unroll
  for (int hh=0;hh<H_;hh++) m[hh] = fmaxf(red[hh][0], red[hh][1]);
  bool allmasked = (m[0] <= -8.0e15f); // same adjacency row for all heads
  __syncthreads();

  // pass 2: p = exp(e - m), accumulate sparse PV
  float acc[H_] = {0.f,0.f,0.f,0.f};
  float lsum[H_] = {0.f,0.f,0.f,0.f};
  const float* WhB = Wh + (size_t)b*H_*N_*F_;
  for (int base=0; base<N_; base+=128){
    int j = base + t;
    float a = adjL[j];
    #pragma unroll
    for (int hh=0;hh<H_;hh++){
      float p;
      if (a > 0.f){
        float e = sh[hh] + tbase[hh*N_+j];
        e = (e>0.f)? e : 0.2f*e;
        p = expf(e - m[hh]);
      } else {
        p = allmasked ? 1.0f : 0.0f;
      }
      pbuf[hh][t] = p;
      lsum[hh] += p;
    }
    __syncthreads();
    for (int jj=0; jj<128; jj++){
      if (adjL[base+jj] > 0.f || allmasked){
        int j2 = base + jj;
        #pragma unroll
        for (int hh=0;hh<H_;hh++){
          acc[hh] += pbuf[hh][jj] * WhB[((size_t)hh*N_ + j2)*F_ + t];
        }
      }
    }
    __syncthreads();
  }

  // reduce softmax denominators across the block
  #pragma unroll
  for (int hh=0;hh<H_;hh++){
    float v = lsum[hh];
    #pragma unroll
    for (int off=32; off>0; off>>=1) v += __shfl_down(v, off);
    if ((t&63)==0) red[hh][t>>6]=v;
  }
  __syncthreads();
  #pragma unroll
  for (int hh=0;hh<H_;hh++){
    float sum = red[hh][0]+red[hh][1];
    float v = acc[hh]/sum;
    v = (v>0.f)? v : expm1f(v);      // elu
    hpL[hh*F_+t] = v;
  }
  __syncthreads();

  // fused projection: h_out = concat_h(hp) @ pw[l] + pb[l]
  float o = pb_l[t];
  for (int k=0;k<H_*F_;k++) o += hpL[k]*pw_l[k*F_+t];
  h_out[(size_t)bn*F_+t] = o;
}

// ---------------- Kernel 4: output head ----------------
__global__ void __launch_bounds__(64) out_kernel(
    const float* __restrict__ h,
    const float* __restrict__ deltas,
    const float* __restrict__ alpha,
    const float* __restrict__ beta,
    const float* __restrict__ ow1, const float* __restrict__ ob1,
    const float* __restrict__ ow2, const float* __restrict__ ob2,
    float* __restrict__ out)
{
  int bn = blockIdx.x;
  int t = threadIdx.x;
  __shared__ float hrow[F_];
  hrow[t] = h[(size_t)bn*F_+t];
  hrow[t+64] = h[(size_t)bn*F_+t+64];
  __syncthreads();
  float u = ob1[t];
  for (int k=0;k<F_;k++) u += hrow[k]*ow1[k*64+t];
  u = gelu_f(u);
  float pv = u * ow2[t];
  #pragma unroll
  for (int off=32; off>0; off>>=1) pv += __shfl_down(pv, off);
  if (t==0){
    float prop = pv + ob2[0];
    int n = bn & (N_-1);
    out[bn] = sigmoid_f(alpha[n]) * deltas[bn] + beta[0]*prop;
  }
}

extern "C" void kernel_launch(void* const* d_in, const int* in_sizes, int n_in,
                              void* d_out, int out_size, void* d_ws, size_t ws_size,
                              hipStream_t stream) {
  const float* deltas = (const float*)d_in[0];
  const float* evt    = (const float*)d_in[1];
  const float* adj    = (const float*)d_in[2];
  const float* mw1 = (const float*)d_in[3];
  const float* mb1 = (const float*)d_in[4];
  const float* mw2 = (const float*)d_in[5];
  const float* mb2 = (const float*)d_in[6];
  const float* mw3 = (const float*)d_in[7];
  const float* mb3 = (const float*)d_in[8];
  const float* gw1 = (const float*)d_in[9];
  const float* gb1 = (const float*)d_in[10];
  const float* gw2 = (const float*)d_in[11];
  const float* gb2 = (const float*)d_in[12];
  const float* Wg  = (const float*)d_in[13];
  const float* a_src = (const float*)d_in[14];
  const float* a_dst = (const float*)d_in[15];
  const float* pw = (const float*)d_in[16];
  const float* pb = (const float*)d_in[17];
  const float* ow1 = (const float*)d_in[18];
  const float* ob1 = (const float*)d_in[19];
  const float* ow2 = (const float*)d_in[20];
  const float* ob2 = (const float*)d_in[21];
  const float* alpha = (const float*)d_in[22];
  const float* beta  = (const float*)d_in[23];
  float* out = (float*)d_out;

  float* ws = (float*)d_ws;
  float* hA = ws;
  float* hB = hA + (size_t)B_*N_*F_;
  float* Wh = hB + (size_t)B_*N_*F_;
  float* sA = Wh + (size_t)B_*H_*N_*F_;
  float* tA = sA + (size_t)B_*H_*N_;

  int BN = B_*N_;
  mlp_kernel<<<BN,128,0,stream>>>(deltas,evt,mw1,mb1,mw2,mb2,mw3,mb3,gw1,gb1,gw2,gb2,hA);
  const float* hin = hA; float* hout = hB;
  for (int l=0;l<2;l++){
    wh_kernel<<<BN,128,0,stream>>>(hin,
        Wg + (size_t)l*H_*F_*F_, a_src + (size_t)l*H_*F_, a_dst + (size_t)l*H_*F_,
        Wh, sA, tA);
    attn_kernel<<<BN,128,0,stream>>>(adj, Wh, sA, tA,
        pw + (size_t)l*H_*F_*F_, pb + (size_t)l*F_, hout);
    float* tmp = (float*)hin; hin = hout; hout = tmp;
  }
  out_kernel<<<BN,64,0,stream>>>(hin, deltas, alpha, beta, ow1, ob1, ow2, ob2, out);
}

// Round 2
// 1043.483 us; speedup vs baseline: 1.6692x; 1.6692x over previous
//
#include <hip/hip_runtime.h>
#include <hip/hip_bf16.h>
#include <math.h>

#define B_ 4
#define N_ 2048
#define F_ 128
#define H_ 4
#define NEG_BIG_F -9.0e15f

typedef float v4 __attribute__((ext_vector_type(4)));

__device__ __forceinline__ float gelu_f(float x){
  return 0.5f*x*(1.0f+erff(x*0.70710678118654752f));
}
__device__ __forceinline__ float sigmoid_f(float x){
  return 1.0f/(1.0f+__expf(-x));
}

// ---------------- Kernel 0: adjacency -> bitmask (u32 words) ----------------
__global__ void __launch_bounds__(256) mask_kernel(
    const float* __restrict__ adj, unsigned* __restrict__ maskWS)
{
  int row = blockIdx.x;   // 0..B*N-1
  int t = threadIdx.x;
  __shared__ unsigned char bytes[256];
  const float* a = adj + (size_t)row*N_;
  unsigned m = 0;
  #pragma unroll
  for (int q=0;q<8;q++) m |= (a[t*8+q] > 0.f ? 1u : 0u) << q;
  bytes[t] = (unsigned char)m;
  __syncthreads();
  if (t < 64){
    unsigned w = (unsigned)bytes[t*4] | ((unsigned)bytes[t*4+1]<<8)
               | ((unsigned)bytes[t*4+2]<<16) | ((unsigned)bytes[t*4+3]<<24);
    maskWS[(size_t)row*64 + t] = w;
  }
}

// ---------------- Kernel 1: tiled MLP, 16 rows/block ----------------
__global__ void __launch_bounds__(256) mlp_kernel(
    const float* __restrict__ deltas, const float* __restrict__ evt,
    const float* __restrict__ mw1, const float* __restrict__ mb1,
    const float* __restrict__ mw2, const float* __restrict__ mb2,
    const float* __restrict__ mw3, const float* __restrict__ mb3,
    const float* __restrict__ gw1, const float* __restrict__ gb1,
    const float* __restrict__ gw2, const float* __restrict__ gb2,
    float* __restrict__ h_out)
{
  int row0 = blockIdx.x * 16;
  int t = threadIdx.x;
  int il = t >> 4;        // 0..15 row
  int fg = t & 15;        // 0..15 f-group of 8
  int f0 = fg * 8;
  __shared__ float combL[16][132];
  __shared__ float m1L[16][132];
  __shared__ float g1L[16][66];

  float acc1[8], accg[8];
  #pragma unroll
  for (int q=0;q<8;q++) acc1[q] = mb1[f0+q];
  #pragma unroll
  for (int q=0;q<8;q++) accg[q] = (fg<8) ? gb1[f0+q] : 0.f;

  for (int kc = 0; kc < 385; kc += 128){
    int klen = 385 - kc; if (klen > 128) klen = 128;
    __syncthreads();
    for (int idx = t; idx < 16*128; idx += 256){
      int i = idx >> 7, k = idx & 127;
      int kg = kc + k;
      float val = 0.f;
      if (kg < 385) val = (kg==0) ? deltas[row0+i] : evt[(size_t)(row0+i)*384 + (kg-1)];
      combL[i][k] = val;
    }
    __syncthreads();
    for (int k = 0; k < klen; k++){
      float c = combL[il][k];
      const float* w1 = mw1 + (size_t)(kc+k)*F_ + f0;
      v4 wa = *(const v4*)w1;
      v4 wb = *(const v4*)(w1+4);
      acc1[0] += c*wa.x; acc1[1] += c*wa.y; acc1[2] += c*wa.z; acc1[3] += c*wa.w;
      acc1[4] += c*wb.x; acc1[5] += c*wb.y; acc1[6] += c*wb.z; acc1[7] += c*wb.w;
      if (fg < 8){
        const float* wg = gw1 + (size_t)(kc+k)*64 + f0;
        v4 ga = *(const v4*)wg;
        v4 gb = *(const v4*)(wg+4);
        accg[0] += c*ga.x; accg[1] += c*ga.y; accg[2] += c*ga.z; accg[3] += c*ga.w;
        accg[4] += c*gb.x; accg[5] += c*gb.y; accg[6] += c*gb.z; accg[7] += c*gb.w;
      }
    }
  }
  __syncthreads();
  #pragma unroll
  for (int q=0;q<8;q++) m1L[il][f0+q] = gelu_f(acc1[q]);
  if (fg < 8){
    #pragma unroll
    for (int q=0;q<8;q++) g1L[il][f0+q] = gelu_f(accg[q]);
  }
  __syncthreads();

  // stage 2: m2 = gelu(m1@mw2+mb2); gate pre-act = g1@gw2+gb2
  float acc2[8], acg2[8];
  #pragma unroll
  for (int q=0;q<8;q++){ acc2[q] = mb2[f0+q]; acg2[q] = gb2[f0+q]; }
  for (int k=0;k<F_;k++){
    float c = m1L[il][k];
    const float* w2 = mw2 + (size_t)k*F_ + f0;
    v4 wa = *(const v4*)w2; v4 wb = *(const v4*)(w2+4);
    acc2[0]+=c*wa.x; acc2[1]+=c*wa.y; acc2[2]+=c*wa.z; acc2[3]+=c*wa.w;
    acc2[4]+=c*wb.x; acc2[5]+=c*wb.y; acc2[6]+=c*wb.z; acc2[7]+=c*wb.w;
  }
  for (int k=0;k<64;k++){
    float c = g1L[il][k];
    const float* wg = gw2 + (size_t)k*F_ + f0;
    v4 wa = *(const v4*)wg; v4 wb = *(const v4*)(wg+4);
    acg2[0]+=c*wa.x; acg2[1]+=c*wa.y; acg2[2]+=c*wa.z; acg2[3]+=c*wa.w;
    acg2[4]+=c*wb.x; acg2[5]+=c*wb.y; acg2[6]+=c*wb.z; acg2[7]+=c*wb.w;
  }
  __syncthreads();
  #pragma unroll
  for (int q=0;q<8;q++) combL[il][f0+q] = gelu_f(acc2[q]);  // reuse combL as m2
  __syncthreads();

  float acc3[8];
  #pragma unroll
  for (int q=0;q<8;q++) acc3[q] = mb3[f0+q];
  for (int k=0;k<F_;k++){
    float c = combL[il][k];
    const float* w3 = mw3 + (size_t)k*F_ + f0;
    v4 wa = *(const v4*)w3; v4 wb = *(const v4*)(w3+4);
    acc3[0]+=c*wa.x; acc3[1]+=c*wa.y; acc3[2]+=c*wa.z; acc3[3]+=c*wa.w;
    acc3[4]+=c*wb.x; acc3[5]+=c*wb.y; acc3[6]+=c*wb.z; acc3[7]+=c*wb.w;
  }
  float* out = h_out + (size_t)(row0+il)*F_ + f0;
  #pragma unroll
  for (int q=0;q<8;q++) out[q] = acc3[q] * sigmoid_f(acg2[q]);
}

// ---------------- Kernel 2: Wh = h @ Wg[l,h], s,t dots; 64 rows/block ----------------
__global__ void __launch_bounds__(256) wh_kernel(
    const float* __restrict__ h,
    const float* __restrict__ Wg_l,     // H*F*F
    const float* __restrict__ asrc_l,   // H*F
    const float* __restrict__ adst_l,
    float* __restrict__ Wh,             // [bh][n][f]
    float* __restrict__ sArr,
    float* __restrict__ tArr)
{
  int v = blockIdx.x;           // bh(16) x ntile(32)
  int itile = v & 31;
  int bh = v >> 5;
  int b = bh >> 2, hh = bh & 3;
  int n0 = itile * 64;
  int t = threadIdx.x;
  int fi = t & 31, ig = t >> 5;     // f = fi*4; i = ig*8 + r
  int f0 = fi*4, i0 = ig*8;

  __shared__ float hT[128][72];
  for (int idx = t; idx < 64*128; idx += 256){
    int i = idx >> 7, k = idx & 127;
    hT[k][i] = h[(size_t)(b*N_ + n0 + i)*F_ + k];
  }
  __syncthreads();

  const float* W = Wg_l + (size_t)hh*F_*F_;
  v4 acc[8];
  #pragma unroll
  for (int r=0;r<8;r++) acc[r] = (v4)0.f;
  for (int k=0;k<F_;k++){
    v4 w = *(const v4*)(W + (size_t)k*F_ + f0);
    v4 ha = *(const v4*)&hT[k][i0];
    v4 hb = *(const v4*)&hT[k][i0+4];
    acc[0] += ha.x*w; acc[1] += ha.y*w; acc[2] += ha.z*w; acc[3] += ha.w*w;
    acc[4] += hb.x*w; acc[5] += hb.y*w; acc[6] += hb.z*w; acc[7] += hb.w*w;
  }
  v4 as = *(const v4*)(asrc_l + (size_t)hh*F_ + f0);
  v4 ad = *(const v4*)(adst_l + (size_t)hh*F_ + f0);
  size_t base = ((size_t)bh*N_ + n0 + i0);
  #pragma unroll
  for (int r=0;r<8;r++){
    *(v4*)(Wh + (base + r)*F_ + f0) = acc[r];
    float sp = acc[r].x*as.x + acc[r].y*as.y + acc[r].z*as.z + acc[r].w*as.w;
    float tp = acc[r].x*ad.x + acc[r].y*ad.y + acc[r].z*ad.z + acc[r].w*ad.w;
    #pragma unroll
    for (int m2=16;m2>0;m2>>=1){
      sp += __shfl_xor(sp, m2);
      tp += __shfl_xor(tp, m2);
    }
    if (fi == 0){
      sArr[base + r] = sp;
      tArr[base + r] = tp;
    }
  }
}

// ---------------- Kernel 3: dense tiled masked-softmax + PV; 64 rows/block ----------------
#define TI 64
#define TJ 32
__global__ void __launch_bounds__(256) attn_kernel(
    const unsigned* __restrict__ maskWS,
    const float* __restrict__ WhWS,
    const float* __restrict__ sArr,
    const float* __restrict__ tArr,
    float* __restrict__ hpWS)
{
  // XCD swizzle: consecutive blockIdx round-robin XCDs; make same-bh blocks share an XCD
  int v = blockIdx.x;           // 512 blocks
  int seq = v >> 3, lane8 = v & 7;
  int bh = (seq >> 5)*8 + lane8;    // 0..15
  int itile = seq & 31;
  int b = bh >> 2;
  int n0 = itile * TI;
  int t = threadIdx.x;
  // mapping A (softmax): il = row, jl = j-lane
  int il = t >> 2, jl = t & 3;
  // mapping B (PV): f0 = 4*fi, i0 = 8*ig
  int fi = t & 31, ig = t >> 5;
  int f0 = fi*4, i0 = ig*8;

  __shared__ float tvec[N_];
  __shared__ unsigned maskw[TI][65];
  __shared__ float whT[TJ][F_];
  __shared__ float pbuf[TJ][72];
  __shared__ float lsumRow[TI];

  const float* tp = tArr + (size_t)bh*N_;
  #pragma unroll
  for (int q=0;q<8;q++) tvec[t + q*256] = tp[t + q*256];
  const unsigned* mrow = maskWS + ((size_t)b*N_ + n0)*64;
  #pragma unroll
  for (int q=0;q<16;q++){
    int idx = t + q*256;
    maskw[idx>>6][idx&63] = mrow[idx];
  }
  float s_il = sArr[(size_t)bh*N_ + n0 + il];
  __syncthreads();

  // phase 1: per-row max over active j
  float mx = NEG_BIG_F;
  for (int w = jl; w < 64; w += 4){
    unsigned wd = maskw[il][w];
    while (wd){
      int k = __builtin_ctz(wd); wd &= wd - 1;
      float e = s_il + tvec[w*32 + k];
      e = e > 0.f ? e : 0.2f*e;
      mx = fmaxf(mx, e);
    }
  }
  mx = fmaxf(mx, __shfl_xor(mx, 1));
  mx = fmaxf(mx, __shfl_xor(mx, 2));
  bool am = (mx == NEG_BIG_F);   // fully masked row -> uniform softmax

  v4 acc[8];
  #pragma unroll
  for (int r=0;r<8;r++) acc[r] = (v4)0.f;
  float lsum = 0.f;

  const float* whbase = WhWS + (size_t)bh*N_*F_;
  for (int c = 0; c < N_/TJ; c++){
    int j0 = c*TJ;
    __syncthreads();
    // stage Wh tile (32x128) -> whT
    {
      const v4* s4 = (const v4*)(whbase + (size_t)j0*F_) + t*4;
      v4* dst = (v4*)whT;
      dst[t*4+0] = s4[0]; dst[t*4+1] = s4[1];
      dst[t*4+2] = s4[2]; dst[t*4+3] = s4[3];
    }
    // fill pbuf (mapping A)
    {
      unsigned wd = maskw[il][j0 >> 5];
      #pragma unroll
      for (int k=0;k<8;k++){
        int jj = jl + 4*k;
        float e = s_il + tvec[j0 + jj];
        e = e > 0.f ? e : 0.2f*e;
        unsigned bit = (wd >> jj) & 1u;
        float p = bit ? __expf(e - mx) : (am ? 1.0f : 0.0f);
        pbuf[jj][il] = p;
        lsum += p;
      }
    }
    __syncthreads();
    // PV (mapping B)
    #pragma unroll 4
    for (int jj=0;jj<TJ;jj++){
      v4 w = *(const v4*)&whT[jj][f0];
      v4 pa = *(const v4*)&pbuf[jj][i0];
      v4 pb2 = *(const v4*)&pbuf[jj][i0+4];
      acc[0] += pa.x*w; acc[1] += pa.y*w; acc[2] += pa.z*w; acc[3] += pa.w*w;
      acc[4] += pb2.x*w; acc[5] += pb2.y*w; acc[6] += pb2.z*w; acc[7] += pb2.w*w;
    }
  }

  lsum += __shfl_xor(lsum, 1);
  lsum += __shfl_xor(lsum, 2);
  if (jl == 0) lsumRow[il] = lsum;
  __syncthreads();

  float* outp = hpWS + ((size_t)bh*N_ + n0 + i0)*F_ + f0;
  #pragma unroll
  for (int r=0;r<8;r++){
    float inv = 1.0f / lsumRow[i0+r];
    v4 vv = acc[r] * inv;
    v4 o;
    o.x = vv.x > 0.f ? vv.x : expm1f(vv.x);
    o.y = vv.y > 0.f ? vv.y : expm1f(vv.y);
    o.z = vv.z > 0.f ? vv.z : expm1f(vv.z);
    o.w = vv.w > 0.f ? vv.w : expm1f(vv.w);
    *(v4*)(outp + (size_t)r*F_) = o;
  }
}

// ---------------- Kernel 4: projection h = concat_h(hp) @ pw + pb; 32 rows/block ----------------
__global__ void __launch_bounds__(256) proj_kernel(
    const float* __restrict__ hpWS,
    const float* __restrict__ pw_l,   // (H*F, F)
    const float* __restrict__ pb_l,   // (F)
    float* __restrict__ h_out)
{
  int v = blockIdx.x;          // b(4) x ntile(64)
  int b = v >> 6;
  int n0 = (v & 63) * 32;
  int t = threadIdx.x;
  int fi = t & 31, ig = t >> 5;    // f = fi*4; i = ig*4 + r (8x4=32 rows)
  int f0 = fi*4, i0 = ig*4;

  __shared__ float hpT[128][40];
  v4 acc[4];
  v4 bias = *(const v4*)(pb_l + f0);
  #pragma unroll
  for (int r=0;r<4;r++) acc[r] = bias;

  for (int kh=0; kh<H_; kh++){
    __syncthreads();
    for (int idx = t; idx < 32*128; idx += 256){
      int i = idx >> 7, kf = idx & 127;
      hpT[kf][i] = hpWS[((size_t)(b*H_+kh)*N_ + n0 + i)*F_ + kf];
    }
    __syncthreads();
    const float* pwk = pw_l + (size_t)kh*F_*F_;
    for (int kf=0;kf<F_;kf++){
      v4 w = *(const v4*)(pwk + (size_t)kf*F_ + f0);
      v4 pa = *(const v4*)&hpT[kf][i0];
      acc[0] += pa.x*w; acc[1] += pa.y*w; acc[2] += pa.z*w; acc[3] += pa.w*w;
    }
  }
  #pragma unroll
  for (int r=0;r<4;r++)
    *(v4*)(h_out + (size_t)(b*N_ + n0 + i0 + r)*F_ + f0) = acc[r];
}

// ---------------- Kernel 5: output head; 32 rows/block ----------------
__global__ void __launch_bounds__(256) out_kernel(
    const float* __restrict__ h,
    const float* __restrict__ deltas,
    const float* __restrict__ alpha,
    const float* __restrict__ beta,
    const float* __restrict__ ow1, const float* __restrict__ ob1,
    const float* __restrict__ ow2, const float* __restrict__ ob2,
    float* __restrict__ out)
{
  int row0 = blockIdx.x * 32;
  int t = threadIdx.x;
  int il = t >> 3, fg = t & 7;   // 32 rows x 8 groups of 8 f
  int f0 = fg * 8;
  __shared__ float hL[32][132];
  for (int idx = t; idx < 32*128; idx += 256){
    int i = idx >> 7, k = idx & 127;
    hL[i][k] = h[(size_t)(row0+i)*F_ + k];
  }
  __syncthreads();
  float acc[8];
  #pragma unroll
  for (int q=0;q<8;q++) acc[q] = ob1[f0+q];
  for (int k=0;k<F_;k++){
    float c = hL[il][k];
    const float* w = ow1 + (size_t)k*64 + f0;
    v4 wa = *(const v4*)w; v4 wb = *(const v4*)(w+4);
    acc[0]+=c*wa.x; acc[1]+=c*wa.y; acc[2]+=c*wa.z; acc[3]+=c*wa.w;
    acc[4]+=c*wb.x; acc[5]+=c*wb.y; acc[6]+=c*wb.z; acc[7]+=c*wb.w;
  }
  float pp = 0.f;
  #pragma unroll
  for (int q=0;q<8;q++) pp += gelu_f(acc[q]) * ow2[f0+q];
  pp += __shfl_xor(pp, 1);
  pp += __shfl_xor(pp, 2);
  pp += __shfl_xor(pp, 4);
  if (fg == 0){
    int row = row0 + il;
    int n = row & (N_-1);
    float prop = pp + ob2[0];
    out[row] = sigmoid_f(alpha[n]) * deltas[row] + beta[0]*prop;
  }
}

extern "C" void kernel_launch(void* const* d_in, const int* in_sizes, int n_in,
                              void* d_out, int out_size, void* d_ws, size_t ws_size,
                              hipStream_t stream) {
  const float* deltas = (const float*)d_in[0];
  const float* evt    = (const float*)d_in[1];
  const float* adj    = (const float*)d_in[2];
  const float* mw1 = (const float*)d_in[3];
  const float* mb1 = (const float*)d_in[4];
  const float* mw2 = (const float*)d_in[5];
  const float* mb2 = (const float*)d_in[6];
  const float* mw3 = (const float*)d_in[7];
  const float* mb3 = (const float*)d_in[8];
  const float* gw1 = (const float*)d_in[9];
  const float* gb1 = (const float*)d_in[10];
  const float* gw2 = (const float*)d_in[11];
  const float* gb2 = (const float*)d_in[12];
  const float* Wg  = (const float*)d_in[13];
  const float* a_src = (const float*)d_in[14];
  const float* a_dst = (const float*)d_in[15];
  const float* pw = (const float*)d_in[16];
  const float* pb = (const float*)d_in[17];
  const float* ow1 = (const float*)d_in[18];
  const float* ob1 = (const float*)d_in[19];
  const float* ow2 = (const float*)d_in[20];
  const float* ob2 = (const float*)d_in[21];
  const float* alpha = (const float*)d_in[22];
  const float* beta  = (const float*)d_in[23];
  float* out = (float*)d_out;

  float* ws = (float*)d_ws;
  float* hA = ws;                                  // B*N*F
  float* hB = hA + (size_t)B_*N_*F_;               // B*N*F
  float* Wh = hB + (size_t)B_*N_*F_;               // B*H*N*F
  float* hp = Wh + (size_t)B_*H_*N_*F_;            // B*H*N*F
  float* sA = hp + (size_t)B_*H_*N_*F_;            // B*H*N
  float* tA = sA + (size_t)B_*H_*N_;               // B*H*N
  unsigned* maskWS = (unsigned*)(tA + (size_t)B_*H_*N_);  // B*N*64 words

  int BN = B_*N_;
  mask_kernel<<<BN, 256, 0, stream>>>(adj, maskWS);
  mlp_kernel<<<BN/16, 256, 0, stream>>>(deltas,evt,mw1,mb1,mw2,mb2,mw3,mb3,gw1,gb1,gw2,gb2,hA);
  const float* hin = hA; float* hout = hB;
  for (int l=0;l<2;l++){
    wh_kernel<<<16*32, 256, 0, stream>>>(hin,
        Wg + (size_t)l*H_*F_*F_, a_src + (size_t)l*H_*F_, a_dst + (size_t)l*H_*F_,
        Wh, sA, tA);
    attn_kernel<<<512, 256, 0, stream>>>(maskWS, Wh, sA, tA, hp);
    proj_kernel<<<256, 256, 0, stream>>>(hp,
        pw + (size_t)l*H_*F_*F_, pb + (size_t)l*F_, hout);
    float* tmp = (float*)hin; hin = hout; hout = tmp;
  }
  out_kernel<<<BN/32, 256, 0, stream>>>(hin, deltas, alpha, beta, ow1, ob1, ow2, ob2, out);
}

// Round 3
// 783.717 us; speedup vs baseline: 2.2225x; 1.3315x over previous
//
#include <hip/hip_runtime.h>
#include <hip/hip_bf16.h>
#include <math.h>

#define B_ 4
#define N_ 2048
#define F_ 128
#define H_ 4
#define NEG_BIG_F -9.0e15f

typedef float v4 __attribute__((ext_vector_type(4)));

__device__ __forceinline__ float gelu_f(float x){
  return 0.5f*x*(1.0f+erff(x*0.70710678118654752f));
}
__device__ __forceinline__ float sigmoid_f(float x){
  return 1.0f/(1.0f+__expf(-x));
}

// ---------------- Kernel 0: adjacency -> bitmask (u32 words) ----------------
__global__ void __launch_bounds__(256) mask_kernel(
    const float* __restrict__ adj, unsigned* __restrict__ maskWS)
{
  int row = blockIdx.x;   // 0..B*N-1
  int t = threadIdx.x;
  __shared__ unsigned char bytes[256];
  const float* a = adj + (size_t)row*N_;
  unsigned m = 0;
  #pragma unroll
  for (int q=0;q<8;q++) m |= (a[t*8+q] > 0.f ? 1u : 0u) << q;
  bytes[t] = (unsigned char)m;
  __syncthreads();
  if (t < 64){
    unsigned w = (unsigned)bytes[t*4] | ((unsigned)bytes[t*4+1]<<8)
               | ((unsigned)bytes[t*4+2]<<16) | ((unsigned)bytes[t*4+3]<<24);
    maskWS[(size_t)row*64 + t] = w;
  }
}

// ---------------- Kernel 1a: stage-1 MLP: m1 = gelu(x@mw1+mb1), g1 = gelu(x@gw1+gb1) ----
// BM=16 rows/block, 512 blocks, 256 threads. Output s1ws[row][0:128]=m1, [128:192]=g1.
__global__ void __launch_bounds__(256) mlp1_kernel(
    const float* __restrict__ deltas, const float* __restrict__ evt,
    const float* __restrict__ mw1, const float* __restrict__ mb1,
    const float* __restrict__ gw1, const float* __restrict__ gb1,
    float* __restrict__ s1ws)
{
  int row0 = blockIdx.x * 16;
  int t = threadIdx.x;
  __shared__ float As[16][392];   // 16 rows x 385 (padded)

  for (int idx = t; idx < 16*385; idx += 256){
    int i = idx / 385;
    int k = idx - i*385;
    As[i][k] = (k==0) ? deltas[row0+i] : evt[(size_t)(row0+i)*384 + (k-1)];
  }
  __syncthreads();

  // pass 1: m-path, 128 cols. cg=t&31 (4 cols), rg=t>>5 (2 rows)
  {
    int cg = t & 31, rg = t >> 5;
    int c = cg*4;
    int r0 = rg*2;
    v4 acc0 = (v4)0.f, acc1 = (v4)0.f;
    #pragma unroll 4
    for (int k=0;k<385;k++){
      v4 w = *(const v4*)(mw1 + (size_t)k*128 + c);
      float a0 = As[r0][k], a1 = As[r0+1][k];
      acc0 += a0*w; acc1 += a1*w;
    }
    v4 bias = *(const v4*)(mb1 + c);
    acc0 += bias; acc1 += bias;
    v4 o0, o1;
    o0.x=gelu_f(acc0.x); o0.y=gelu_f(acc0.y); o0.z=gelu_f(acc0.z); o0.w=gelu_f(acc0.w);
    o1.x=gelu_f(acc1.x); o1.y=gelu_f(acc1.y); o1.z=gelu_f(acc1.z); o1.w=gelu_f(acc1.w);
    *(v4*)(s1ws + (size_t)(row0+r0  )*192 + c) = o0;
    *(v4*)(s1ws + (size_t)(row0+r0+1)*192 + c) = o1;
  }

  // pass 2: g-path, 64 cols. cg2=t&15 (4 cols), il=t>>4 (1 row)
  {
    int cg2 = t & 15, il = t >> 4;
    int c = cg2*4;
    v4 acc = (v4)0.f;
    #pragma unroll 4
    for (int k=0;k<385;k++){
      v4 w = *(const v4*)(gw1 + (size_t)k*64 + c);
      float a = As[il][k];
      acc += a*w;
    }
    acc += *(const v4*)(gb1 + c);
    v4 o;
    o.x=gelu_f(acc.x); o.y=gelu_f(acc.y); o.z=gelu_f(acc.z); o.w=gelu_f(acc.w);
    *(v4*)(s1ws + (size_t)(row0+il)*192 + 128 + c) = o;
  }
}

// ---------------- Kernel 1b: stages 2+3: m2=gelu(m1@mw2+mb2); gp=g1@gw2+gb2;
//                  h = (m2@mw3+mb3)*sigmoid(gp). BM=16, 512 blocks, 256 thr. ----
__global__ void __launch_bounds__(256) mlp2_kernel(
    const float* __restrict__ s1ws,
    const float* __restrict__ mw2, const float* __restrict__ mb2,
    const float* __restrict__ mw3, const float* __restrict__ mb3,
    const float* __restrict__ gw2, const float* __restrict__ gb2,
    float* __restrict__ h_out)
{
  int row0 = blockIdx.x * 16;
  int t = threadIdx.x;
  __shared__ float s1[16][196];    // [i][0:128]=m1, [128:192]=g1
  __shared__ float m2s[16][132];
  __shared__ float gp[16][132];

  for (int idx = t; idx < 16*48; idx += 256){
    int i = idx / 48;
    int c4 = idx - i*48;
    *(v4*)&s1[i][c4*4] = *(const v4*)(s1ws + (size_t)(row0+i)*192 + c4*4);
  }
  __syncthreads();

  // stage 2: cg=t>>2 (0..63), rg=t&3 (4 rows each). waves 0-1: m-cols; waves 2-3: g-cols
  {
    int cg = t >> 2, rg = t & 3;
    int r0 = rg*4;
    v4 acc0=(v4)0.f, acc1=(v4)0.f, acc2=(v4)0.f, acc3=(v4)0.f;
    if (cg < 32){
      int c = cg*4;
      #pragma unroll 4
      for (int k=0;k<128;k++){
        v4 w = *(const v4*)(mw2 + (size_t)k*128 + c);
        acc0 += s1[r0  ][k]*w;
        acc1 += s1[r0+1][k]*w;
        acc2 += s1[r0+2][k]*w;
        acc3 += s1[r0+3][k]*w;
      }
      v4 bias = *(const v4*)(mb2 + c);
      acc0+=bias; acc1+=bias; acc2+=bias; acc3+=bias;
      v4 o;
      o.x=gelu_f(acc0.x); o.y=gelu_f(acc0.y); o.z=gelu_f(acc0.z); o.w=gelu_f(acc0.w); *(v4*)&m2s[r0  ][c]=o;
      o.x=gelu_f(acc1.x); o.y=gelu_f(acc1.y); o.z=gelu_f(acc1.z); o.w=gelu_f(acc1.w); *(v4*)&m2s[r0+1][c]=o;
      o.x=gelu_f(acc2.x); o.y=gelu_f(acc2.y); o.z=gelu_f(acc2.z); o.w=gelu_f(acc2.w); *(v4*)&m2s[r0+2][c]=o;
      o.x=gelu_f(acc3.x); o.y=gelu_f(acc3.y); o.z=gelu_f(acc3.z); o.w=gelu_f(acc3.w); *(v4*)&m2s[r0+3][c]=o;
    } else {
      int c = (cg-32)*4;
      #pragma unroll 4
      for (int k=0;k<64;k++){
        v4 w = *(const v4*)(gw2 + (size_t)k*128 + c);
        acc0 += s1[r0  ][128+k]*w;
        acc1 += s1[r0+1][128+k]*w;
        acc2 += s1[r0+2][128+k]*w;
        acc3 += s1[r0+3][128+k]*w;
      }
      v4 bias = *(const v4*)(gb2 + c);
      *(v4*)&gp[r0  ][c] = acc0+bias;
      *(v4*)&gp[r0+1][c] = acc1+bias;
      *(v4*)&gp[r0+2][c] = acc2+bias;
      *(v4*)&gp[r0+3][c] = acc3+bias;
    }
  }
  __syncthreads();

  // stage 3: cg3=t&31 (4 cols), rg3=t>>5 (2 rows)
  {
    int cg3 = t & 31, rg3 = t >> 5;
    int c = cg3*4;
    int r0 = rg3*2;
    v4 acc0=(v4)0.f, acc1=(v4)0.f;
    #pragma unroll 4
    for (int k=0;k<128;k++){
      v4 w = *(const v4*)(mw3 + (size_t)k*128 + c);
      acc0 += m2s[r0  ][k]*w;
      acc1 += m2s[r0+1][k]*w;
    }
    v4 bias = *(const v4*)(mb3 + c);
    acc0+=bias; acc1+=bias;
    v4 g0 = *(const v4*)&gp[r0][c];
    v4 g1v = *(const v4*)&gp[r0+1][c];
    v4 o0, o1;
    o0.x = acc0.x*sigmoid_f(g0.x); o0.y = acc0.y*sigmoid_f(g0.y);
    o0.z = acc0.z*sigmoid_f(g0.z); o0.w = acc0.w*sigmoid_f(g0.w);
    o1.x = acc1.x*sigmoid_f(g1v.x); o1.y = acc1.y*sigmoid_f(g1v.y);
    o1.z = acc1.z*sigmoid_f(g1v.z); o1.w = acc1.w*sigmoid_f(g1v.w);
    *(v4*)(h_out + (size_t)(row0+r0  )*F_ + c) = o0;
    *(v4*)(h_out + (size_t)(row0+r0+1)*F_ + c) = o1;
  }
}

// ---------------- Kernel 2: Wh = h @ Wg[l,h], s,t dots; 64 rows/block ----------------
__global__ void __launch_bounds__(256) wh_kernel(
    const float* __restrict__ h,
    const float* __restrict__ Wg_l,     // H*F*F
    const float* __restrict__ asrc_l,   // H*F
    const float* __restrict__ adst_l,
    float* __restrict__ Wh,             // [bh][n][f]
    float* __restrict__ sArr,
    float* __restrict__ tArr)
{
  int v = blockIdx.x;           // bh(16) x ntile(32)
  int itile = v & 31;
  int bh = v >> 5;
  int b = bh >> 2, hh = bh & 3;
  int n0 = itile * 64;
  int t = threadIdx.x;
  int fi = t & 31, ig = t >> 5;     // f = fi*4; i = ig*8 + r
  int f0 = fi*4, i0 = ig*8;

  __shared__ float hT[128][72];
  for (int idx = t; idx < 64*128; idx += 256){
    int i = idx >> 7, k = idx & 127;
    hT[k][i] = h[(size_t)(b*N_ + n0 + i)*F_ + k];
  }
  __syncthreads();

  const float* W = Wg_l + (size_t)hh*F_*F_;
  v4 acc[8];
  #pragma unroll
  for (int r=0;r<8;r++) acc[r] = (v4)0.f;
  for (int k=0;k<F_;k++){
    v4 w = *(const v4*)(W + (size_t)k*F_ + f0);
    v4 ha = *(const v4*)&hT[k][i0];
    v4 hb = *(const v4*)&hT[k][i0+4];
    acc[0] += ha.x*w; acc[1] += ha.y*w; acc[2] += ha.z*w; acc[3] += ha.w*w;
    acc[4] += hb.x*w; acc[5] += hb.y*w; acc[6] += hb.z*w; acc[7] += hb.w*w;
  }
  v4 as = *(const v4*)(asrc_l + (size_t)hh*F_ + f0);
  v4 ad = *(const v4*)(adst_l + (size_t)hh*F_ + f0);
  size_t base = ((size_t)bh*N_ + n0 + i0);
  #pragma unroll
  for (int r=0;r<8;r++){
    *(v4*)(Wh + (base + r)*F_ + f0) = acc[r];
    float sp = acc[r].x*as.x + acc[r].y*as.y + acc[r].z*as.z + acc[r].w*as.w;
    float tp = acc[r].x*ad.x + acc[r].y*ad.y + acc[r].z*ad.z + acc[r].w*ad.w;
    #pragma unroll
    for (int m2=16;m2>0;m2>>=1){
      sp += __shfl_xor(sp, m2);
      tp += __shfl_xor(tp, m2);
    }
    if (fi == 0){
      sArr[base + r] = sp;
      tArr[base + r] = tp;
    }
  }
}

// ---------------- Kernel 3: dense tiled masked-softmax + PV; 64 rows/block ----------------
#define TI 64
#define TJ 32
__global__ void __launch_bounds__(256) attn_kernel(
    const unsigned* __restrict__ maskWS,
    const float* __restrict__ WhWS,
    const float* __restrict__ sArr,
    const float* __restrict__ tArr,
    float* __restrict__ hpWS)
{
  int v = blockIdx.x;           // 512 blocks
  int seq = v >> 3, lane8 = v & 7;
  int bh = (seq >> 5)*8 + lane8;    // 0..15
  int itile = seq & 31;
  int b = bh >> 2;
  int n0 = itile * TI;
  int t = threadIdx.x;
  int il = t >> 2, jl = t & 3;
  int fi = t & 31, ig = t >> 5;
  int f0 = fi*4, i0 = ig*8;

  __shared__ float tvec[N_];
  __shared__ unsigned maskw[TI][65];
  __shared__ float whT[TJ][F_];
  __shared__ float pbuf[TJ][72];
  __shared__ float lsumRow[TI];

  const float* tp = tArr + (size_t)bh*N_;
  #pragma unroll
  for (int q=0;q<8;q++) tvec[t + q*256] = tp[t + q*256];
  const unsigned* mrow = maskWS + ((size_t)b*N_ + n0)*64;
  #pragma unroll
  for (int q=0;q<16;q++){
    int idx = t + q*256;
    maskw[idx>>6][idx&63] = mrow[idx];
  }
  float s_il = sArr[(size_t)bh*N_ + n0 + il];
  __syncthreads();

  float mx = NEG_BIG_F;
  for (int w = jl; w < 64; w += 4){
    unsigned wd = maskw[il][w];
    while (wd){
      int k = __builtin_ctz(wd); wd &= wd - 1;
      float e = s_il + tvec[w*32 + k];
      e = e > 0.f ? e : 0.2f*e;
      mx = fmaxf(mx, e);
    }
  }
  mx = fmaxf(mx, __shfl_xor(mx, 1));
  mx = fmaxf(mx, __shfl_xor(mx, 2));
  bool am = (mx == NEG_BIG_F);

  v4 acc[8];
  #pragma unroll
  for (int r=0;r<8;r++) acc[r] = (v4)0.f;
  float lsum = 0.f;

  const float* whbase = WhWS + (size_t)bh*N_*F_;
  for (int c = 0; c < N_/TJ; c++){
    int j0 = c*TJ;
    __syncthreads();
    {
      const v4* s4 = (const v4*)(whbase + (size_t)j0*F_) + t*4;
      v4* dst = (v4*)whT;
      dst[t*4+0] = s4[0]; dst[t*4+1] = s4[1];
      dst[t*4+2] = s4[2]; dst[t*4+3] = s4[3];
    }
    {
      unsigned wd = maskw[il][j0 >> 5];
      #pragma unroll
      for (int k=0;k<8;k++){
        int jj = jl + 4*k;
        float e = s_il + tvec[j0 + jj];
        e = e > 0.f ? e : 0.2f*e;
        unsigned bit = (wd >> jj) & 1u;
        float p = bit ? __expf(e - mx) : (am ? 1.0f : 0.0f);
        pbuf[jj][il] = p;
        lsum += p;
      }
    }
    __syncthreads();
    #pragma unroll 4
    for (int jj=0;jj<TJ;jj++){
      v4 w = *(const v4*)&whT[jj][f0];
      v4 pa = *(const v4*)&pbuf[jj][i0];
      v4 pb2 = *(const v4*)&pbuf[jj][i0+4];
      acc[0] += pa.x*w; acc[1] += pa.y*w; acc[2] += pa.z*w; acc[3] += pa.w*w;
      acc[4] += pb2.x*w; acc[5] += pb2.y*w; acc[6] += pb2.z*w; acc[7] += pb2.w*w;
    }
  }

  lsum += __shfl_xor(lsum, 1);
  lsum += __shfl_xor(lsum, 2);
  if (jl == 0) lsumRow[il] = lsum;
  __syncthreads();

  float* outp = hpWS + ((size_t)bh*N_ + n0 + i0)*F_ + f0;
  #pragma unroll
  for (int r=0;r<8;r++){
    float inv = 1.0f / lsumRow[i0+r];
    v4 vv = acc[r] * inv;
    v4 o;
    o.x = vv.x > 0.f ? vv.x : expm1f(vv.x);
    o.y = vv.y > 0.f ? vv.y : expm1f(vv.y);
    o.z = vv.z > 0.f ? vv.z : expm1f(vv.z);
    o.w = vv.w > 0.f ? vv.w : expm1f(vv.w);
    *(v4*)(outp + (size_t)r*F_) = o;
  }
}

// ---------------- Kernel 4: projection h = concat_h(hp) @ pw + pb; 32 rows/block ----------------
__global__ void __launch_bounds__(256) proj_kernel(
    const float* __restrict__ hpWS,
    const float* __restrict__ pw_l,   // (H*F, F)
    const float* __restrict__ pb_l,   // (F)
    float* __restrict__ h_out)
{
  int v = blockIdx.x;          // b(4) x ntile(64)
  int b = v >> 6;
  int n0 = (v & 63) * 32;
  int t = threadIdx.x;
  int fi = t & 31, ig = t >> 5;
  int f0 = fi*4, i0 = ig*4;

  __shared__ float hpT[128][40];
  v4 acc[4];
  v4 bias = *(const v4*)(pb_l + f0);
  #pragma unroll
  for (int r=0;r<4;r++) acc[r] = bias;

  for (int kh=0; kh<H_; kh++){
    __syncthreads();
    for (int idx = t; idx < 32*128; idx += 256){
      int i = idx >> 7, kf = idx & 127;
      hpT[kf][i] = hpWS[((size_t)(b*H_+kh)*N_ + n0 + i)*F_ + kf];
    }
    __syncthreads();
    const float* pwk = pw_l + (size_t)kh*F_*F_;
    for (int kf=0;kf<F_;kf++){
      v4 w = *(const v4*)(pwk + (size_t)kf*F_ + f0);
      v4 pa = *(const v4*)&hpT[kf][i0];
      acc[0] += pa.x*w; acc[1] += pa.y*w; acc[2] += pa.z*w; acc[3] += pa.w*w;
    }
  }
  #pragma unroll
  for (int r=0;r<4;r++)
    *(v4*)(h_out + (size_t)(b*N_ + n0 + i0 + r)*F_ + f0) = acc[r];
}

// ---------------- Kernel 5: output head; 32 rows/block ----------------
__global__ void __launch_bounds__(256) out_kernel(
    const float* __restrict__ h,
    const float* __restrict__ deltas,
    const float* __restrict__ alpha,
    const float* __restrict__ beta,
    const float* __restrict__ ow1, const float* __restrict__ ob1,
    const float* __restrict__ ow2, const float* __restrict__ ob2,
    float* __restrict__ out)
{
  int row0 = blockIdx.x * 32;
  int t = threadIdx.x;
  int il = t >> 3, fg = t & 7;
  int f0 = fg * 8;
  __shared__ float hL[32][132];
  for (int idx = t; idx < 32*128; idx += 256){
    int i = idx >> 7, k = idx & 127;
    hL[i][k] = h[(size_t)(row0+i)*F_ + k];
  }
  __syncthreads();
  float acc[8];
  #pragma unroll
  for (int q=0;q<8;q++) acc[q] = ob1[f0+q];
  for (int k=0;k<F_;k++){
    float c = hL[il][k];
    const float* w = ow1 + (size_t)k*64 + f0;
    v4 wa = *(const v4*)w; v4 wb = *(const v4*)(w+4);
    acc[0]+=c*wa.x; acc[1]+=c*wa.y; acc[2]+=c*wa.z; acc[3]+=c*wa.w;
    acc[4]+=c*wb.x; acc[5]+=c*wb.y; acc[6]+=c*wb.z; acc[7]+=c*wb.w;
  }
  float pp = 0.f;
  #pragma unroll
  for (int q=0;q<8;q++) pp += gelu_f(acc[q]) * ow2[f0+q];
  pp += __shfl_xor(pp, 1);
  pp += __shfl_xor(pp, 2);
  pp += __shfl_xor(pp, 4);
  if (fg == 0){
    int row = row0 + il;
    int n = row & (N_-1);
    float prop = pp + ob2[0];
    out[row] = sigmoid_f(alpha[n]) * deltas[row] + beta[0]*prop;
  }
}

extern "C" void kernel_launch(void* const* d_in, const int* in_sizes, int n_in,
                              void* d_out, int out_size, void* d_ws, size_t ws_size,
                              hipStream_t stream) {
  const float* deltas = (const float*)d_in[0];
  const float* evt    = (const float*)d_in[1];
  const float* adj    = (const float*)d_in[2];
  const float* mw1 = (const float*)d_in[3];
  const float* mb1 = (const float*)d_in[4];
  const float* mw2 = (const float*)d_in[5];
  const float* mb2 = (const float*)d_in[6];
  const float* mw3 = (const float*)d_in[7];
  const float* mb3 = (const float*)d_in[8];
  const float* gw1 = (const float*)d_in[9];
  const float* gb1 = (const float*)d_in[10];
  const float* gw2 = (const float*)d_in[11];
  const float* gb2 = (const float*)d_in[12];
  const float* Wg  = (const float*)d_in[13];
  const float* a_src = (const float*)d_in[14];
  const float* a_dst = (const float*)d_in[15];
  const float* pw = (const float*)d_in[16];
  const float* pb = (const float*)d_in[17];
  const float* ow1 = (const float*)d_in[18];
  const float* ob1 = (const float*)d_in[19];
  const float* ow2 = (const float*)d_in[20];
  const float* ob2 = (const float*)d_in[21];
  const float* alpha = (const float*)d_in[22];
  const float* beta  = (const float*)d_in[23];
  float* out = (float*)d_out;

  float* ws = (float*)d_ws;
  float* hA = ws;                                  // B*N*F
  float* hB = hA + (size_t)B_*N_*F_;               // B*N*F
  float* Wh = hB + (size_t)B_*N_*F_;               // B*H*N*F
  float* hp = Wh + (size_t)B_*H_*N_*F_;            // B*H*N*F
  float* sA = hp + (size_t)B_*H_*N_*F_;            // B*H*N
  float* tA = sA + (size_t)B_*H_*N_;               // B*H*N
  unsigned* maskWS = (unsigned*)(tA + (size_t)B_*H_*N_);  // B*N*64 words
  float* s1ws = hp;   // reuse hp region: dead until first attn_kernel

  int BN = B_*N_;
  mask_kernel<<<BN, 256, 0, stream>>>(adj, maskWS);
  mlp1_kernel<<<BN/16, 256, 0, stream>>>(deltas, evt, mw1, mb1, gw1, gb1, s1ws);
  mlp2_kernel<<<BN/16, 256, 0, stream>>>(s1ws, mw2, mb2, mw3, mb3, gw2, gb2, hA);
  const float* hin = hA; float* hout = hB;
  for (int l=0;l<2;l++){
    wh_kernel<<<16*32, 256, 0, stream>>>(hin,
        Wg + (size_t)l*H_*F_*F_, a_src + (size_t)l*H_*F_, a_dst + (size_t)l*H_*F_,
        Wh, sA, tA);
    attn_kernel<<<512, 256, 0, stream>>>(maskWS, Wh, sA, tA, hp);
    proj_kernel<<<256, 256, 0, stream>>>(hp,
        pw + (size_t)l*H_*F_*F_, pb + (size_t)l*F_, hout);
    float* tmp = (float*)hin; hin = hout; hout = tmp;
  }
  out_kernel<<<BN/32, 256, 0, stream>>>(hin, deltas, alpha, beta, ow1, ob1, ow2, ob2, out);
}

// Round 4
// 472.206 us; speedup vs baseline: 3.6887x; 1.6597x over previous
//
#include <hip/hip_runtime.h>
#include <hip/hip_bf16.h>
#include <math.h>

#define B_ 4
#define N_ 2048
#define F_ 128
#define H_ 4
#define NEG_BIG_F -9.0e15f

typedef float v4 __attribute__((ext_vector_type(4)));
typedef float f32x16 __attribute__((ext_vector_type(16)));
typedef short s16x8 __attribute__((ext_vector_type(8)));
typedef short s16x4 __attribute__((ext_vector_type(4)));

__device__ __forceinline__ float gelu_f(float x){
  return 0.5f*x*(1.0f+erff(x*0.70710678118654752f));
}
__device__ __forceinline__ float sigmoid_f(float x){
  return 1.0f/(1.0f+__expf(-x));
}
__device__ __forceinline__ short bfbits(float v){
  __hip_bfloat16 h = __float2bfloat16(v);
  short r; __builtin_memcpy(&r, &h, 2); return r;
}
__device__ __forceinline__ float bfback(short s){
  return __uint_as_float(((unsigned)(unsigned short)s) << 16);
}

// ---------------- Kernel 0: adjacency -> transposed bitmask maskT[b][word][n] ----------------
__global__ void __launch_bounds__(256) mask_kernel(
    const float* __restrict__ adj, unsigned* __restrict__ maskT)
{
  int v = blockIdx.x;            // b(4) x 64 tiles of 32 rows
  int b = v >> 6; int n0 = (v & 63) * 32;
  int t = threadIdx.x;
  int r = t >> 3, jg = t & 7;
  __shared__ unsigned mw[32][65];
  const float* arow = adj + (size_t)(b*N_ + n0 + r)*N_;
  for (int wq=0; wq<8; wq++){
    int wdi = jg + 8*wq;
    unsigned bits = 0;
    #pragma unroll
    for (int m=0;m<8;m++){
      v4 a = *(const v4*)(arow + wdi*32 + m*4);
      bits |= (a.x>0.f?1u:0u)<<(m*4);
      bits |= (a.y>0.f?1u:0u)<<(m*4+1);
      bits |= (a.z>0.f?1u:0u)<<(m*4+2);
      bits |= (a.w>0.f?1u:0u)<<(m*4+3);
    }
    mw[r][wdi] = bits;
  }
  __syncthreads();
  #pragma unroll
  for (int q=0;q<8;q++){
    int idx = t + q*256;
    int wdi = idx >> 5, rr = idx & 31;
    maskT[((size_t)b*64 + wdi)*N_ + n0 + rr] = mw[rr][wdi];
  }
}

// ---------------- Kernel 1a: stage-1 MLP ----------------
__global__ void __launch_bounds__(256) mlp1_kernel(
    const float* __restrict__ deltas, const float* __restrict__ evt,
    const float* __restrict__ mw1, const float* __restrict__ mb1,
    const float* __restrict__ gw1, const float* __restrict__ gb1,
    float* __restrict__ s1ws)
{
  int row0 = blockIdx.x * 16;
  int t = threadIdx.x;
  __shared__ float As[16][392];
  for (int idx = t; idx < 16*385; idx += 256){
    int i = idx / 385;
    int k = idx - i*385;
    As[i][k] = (k==0) ? deltas[row0+i] : evt[(size_t)(row0+i)*384 + (k-1)];
  }
  __syncthreads();
  {
    int cg = t & 31, rg = t >> 5;
    int c = cg*4;
    int r0 = rg*2;
    v4 acc0 = (v4)0.f, acc1 = (v4)0.f;
    #pragma unroll 4
    for (int k=0;k<385;k++){
      v4 w = *(const v4*)(mw1 + (size_t)k*128 + c);
      float a0 = As[r0][k], a1 = As[r0+1][k];
      acc0 += a0*w; acc1 += a1*w;
    }
    v4 bias = *(const v4*)(mb1 + c);
    acc0 += bias; acc1 += bias;
    v4 o0, o1;
    o0.x=gelu_f(acc0.x); o0.y=gelu_f(acc0.y); o0.z=gelu_f(acc0.z); o0.w=gelu_f(acc0.w);
    o1.x=gelu_f(acc1.x); o1.y=gelu_f(acc1.y); o1.z=gelu_f(acc1.z); o1.w=gelu_f(acc1.w);
    *(v4*)(s1ws + (size_t)(row0+r0  )*192 + c) = o0;
    *(v4*)(s1ws + (size_t)(row0+r0+1)*192 + c) = o1;
  }
  {
    int cg2 = t & 15, il = t >> 4;
    int c = cg2*4;
    v4 acc = (v4)0.f;
    #pragma unroll 4
    for (int k=0;k<385;k++){
      v4 w = *(const v4*)(gw1 + (size_t)k*64 + c);
      float a = As[il][k];
      acc += a*w;
    }
    acc += *(const v4*)(gb1 + c);
    v4 o;
    o.x=gelu_f(acc.x); o.y=gelu_f(acc.y); o.z=gelu_f(acc.z); o.w=gelu_f(acc.w);
    *(v4*)(s1ws + (size_t)(row0+il)*192 + 128 + c) = o;
  }
}

// ---------------- Kernel 1b: stages 2+3 ----------------
__global__ void __launch_bounds__(256) mlp2_kernel(
    const float* __restrict__ s1ws,
    const float* __restrict__ mw2, const float* __restrict__ mb2,
    const float* __restrict__ mw3, const float* __restrict__ mb3,
    const float* __restrict__ gw2, const float* __restrict__ gb2,
    float* __restrict__ h_out)
{
  int row0 = blockIdx.x * 16;
  int t = threadIdx.x;
  __shared__ float s1[16][196];
  __shared__ float m2s[16][132];
  __shared__ float gp[16][132];
  for (int idx = t; idx < 16*48; idx += 256){
    int i = idx / 48;
    int c4 = idx - i*48;
    *(v4*)&s1[i][c4*4] = *(const v4*)(s1ws + (size_t)(row0+i)*192 + c4*4);
  }
  __syncthreads();
  {
    int cg = t >> 2, rg = t & 3;
    int r0 = rg*4;
    v4 acc0=(v4)0.f, acc1=(v4)0.f, acc2=(v4)0.f, acc3=(v4)0.f;
    if (cg < 32){
      int c = cg*4;
      #pragma unroll 4
      for (int k=0;k<128;k++){
        v4 w = *(const v4*)(mw2 + (size_t)k*128 + c);
        acc0 += s1[r0  ][k]*w;
        acc1 += s1[r0+1][k]*w;
        acc2 += s1[r0+2][k]*w;
        acc3 += s1[r0+3][k]*w;
      }
      v4 bias = *(const v4*)(mb2 + c);
      acc0+=bias; acc1+=bias; acc2+=bias; acc3+=bias;
      v4 o;
      o.x=gelu_f(acc0.x); o.y=gelu_f(acc0.y); o.z=gelu_f(acc0.z); o.w=gelu_f(acc0.w); *(v4*)&m2s[r0  ][c]=o;
      o.x=gelu_f(acc1.x); o.y=gelu_f(acc1.y); o.z=gelu_f(acc1.z); o.w=gelu_f(acc1.w); *(v4*)&m2s[r0+1][c]=o;
      o.x=gelu_f(acc2.x); o.y=gelu_f(acc2.y); o.z=gelu_f(acc2.z); o.w=gelu_f(acc2.w); *(v4*)&m2s[r0+2][c]=o;
      o.x=gelu_f(acc3.x); o.y=gelu_f(acc3.y); o.z=gelu_f(acc3.z); o.w=gelu_f(acc3.w); *(v4*)&m2s[r0+3][c]=o;
    } else {
      int c = (cg-32)*4;
      #pragma unroll 4
      for (int k=0;k<64;k++){
        v4 w = *(const v4*)(gw2 + (size_t)k*128 + c);
        acc0 += s1[r0  ][128+k]*w;
        acc1 += s1[r0+1][128+k]*w;
        acc2 += s1[r0+2][128+k]*w;
        acc3 += s1[r0+3][128+k]*w;
      }
      v4 bias = *(const v4*)(gb2 + c);
      *(v4*)&gp[r0  ][c] = acc0+bias;
      *(v4*)&gp[r0+1][c] = acc1+bias;
      *(v4*)&gp[r0+2][c] = acc2+bias;
      *(v4*)&gp[r0+3][c] = acc3+bias;
    }
  }
  __syncthreads();
  {
    int cg3 = t & 31, rg3 = t >> 5;
    int c = cg3*4;
    int r0 = rg3*2;
    v4 acc0=(v4)0.f, acc1=(v4)0.f;
    #pragma unroll 4
    for (int k=0;k<128;k++){
      v4 w = *(const v4*)(mw3 + (size_t)k*128 + c);
      acc0 += m2s[r0  ][k]*w;
      acc1 += m2s[r0+1][k]*w;
    }
    v4 bias = *(const v4*)(mb3 + c);
    acc0+=bias; acc1+=bias;
    v4 g0 = *(const v4*)&gp[r0][c];
    v4 g1v = *(const v4*)&gp[r0+1][c];
    v4 o0, o1;
    o0.x = acc0.x*sigmoid_f(g0.x); o0.y = acc0.y*sigmoid_f(g0.y);
    o0.z = acc0.z*sigmoid_f(g0.z); o0.w = acc0.w*sigmoid_f(g0.w);
    o1.x = acc1.x*sigmoid_f(g1v.x); o1.y = acc1.y*sigmoid_f(g1v.y);
    o1.z = acc1.z*sigmoid_f(g1v.z); o1.w = acc1.w*sigmoid_f(g1v.w);
    *(v4*)(h_out + (size_t)(row0+r0  )*F_ + c) = o0;
    *(v4*)(h_out + (size_t)(row0+r0+1)*F_ + c) = o1;
  }
}

// ---------------- Kernel 2: WhT (bf16 hi/lo, [bh][f][n]) + s,t dots ----------------
__global__ void __launch_bounds__(256) wh_kernel(
    const float* __restrict__ h,
    const float* __restrict__ Wg_l,     // H*F*F
    const float* __restrict__ asrc_l,
    const float* __restrict__ adst_l,
    short* __restrict__ WhT_hi,         // [bh][f][n] bf16 bits
    short* __restrict__ WhT_lo,
    float* __restrict__ sArr,
    float* __restrict__ tArr)
{
  int v = blockIdx.x;           // bh(16) x ntile(32)
  int itile = v & 31;
  int bh = v >> 5;
  int b = bh >> 2, hh = bh & 3;
  int n0 = itile * 64;
  int t = threadIdx.x;
  int i0  = (t & 7) * 8;        // 8 n per thread
  int fo0 = (t >> 3) * 4;       // 4 fo per thread

  __shared__ float hT[128][72];
  __shared__ float sP[4][64], tP[4][64];
  for (int idx = t; idx < 64*128; idx += 256){
    int i = idx >> 7, k = idx & 127;
    hT[k][i] = h[(size_t)(b*N_ + n0 + i)*F_ + k];
  }
  __syncthreads();

  const float* W = Wg_l + (size_t)hh*F_*F_;
  v4 accA[4], accB[4];
  #pragma unroll
  for (int c=0;c<4;c++){ accA[c]=(v4)0.f; accB[c]=(v4)0.f; }
  for (int k=0;k<F_;k++){
    v4 w = *(const v4*)(W + (size_t)k*F_ + fo0);
    v4 ha = *(const v4*)&hT[k][i0];
    v4 hb = *(const v4*)&hT[k][i0+4];
    accA[0]+=w.x*ha; accA[1]+=w.y*ha; accA[2]+=w.z*ha; accA[3]+=w.w*ha;
    accB[0]+=w.x*hb; accB[1]+=w.y*hb; accB[2]+=w.z*hb; accB[3]+=w.w*hb;
  }
  // transposed bf16 hi/lo stores
  #pragma unroll
  for (int c=0;c<4;c++){
    s16x8 hi8, lo8;
    #pragma unroll
    for (int e=0;e<8;e++){
      float x = (e<4) ? accA[c][e] : accB[c][e-4];
      short hb2 = bfbits(x);
      hi8[e] = hb2;
      lo8[e] = bfbits(x - bfback(hb2));
    }
    size_t off = ((size_t)bh*F_ + fo0 + c)*N_ + n0 + i0;
    *(s16x8*)(WhT_hi + off) = hi8;
    *(s16x8*)(WhT_lo + off) = lo8;
  }
  // s,t partials
  v4 as4 = *(const v4*)(asrc_l + hh*F_ + fo0);
  v4 ad4 = *(const v4*)(adst_l + hh*F_ + fo0);
  v4 sva = accA[0]*as4.x + accA[1]*as4.y + accA[2]*as4.z + accA[3]*as4.w;
  v4 svb = accB[0]*as4.x + accB[1]*as4.y + accB[2]*as4.z + accB[3]*as4.w;
  v4 tva = accA[0]*ad4.x + accA[1]*ad4.y + accA[2]*ad4.z + accA[3]*ad4.w;
  v4 tvb = accB[0]*ad4.x + accB[1]*ad4.y + accB[2]*ad4.z + accB[3]*ad4.w;
  #pragma unroll
  for (int m=8;m<=32;m<<=1){
    sva.x+=__shfl_xor(sva.x,m); sva.y+=__shfl_xor(sva.y,m); sva.z+=__shfl_xor(sva.z,m); sva.w+=__shfl_xor(sva.w,m);
    svb.x+=__shfl_xor(svb.x,m); svb.y+=__shfl_xor(svb.y,m); svb.z+=__shfl_xor(svb.z,m); svb.w+=__shfl_xor(svb.w,m);
    tva.x+=__shfl_xor(tva.x,m); tva.y+=__shfl_xor(tva.y,m); tva.z+=__shfl_xor(tva.z,m); tva.w+=__shfl_xor(tva.w,m);
    tvb.x+=__shfl_xor(tvb.x,m); tvb.y+=__shfl_xor(tvb.y,m); tvb.z+=__shfl_xor(tvb.z,m); tvb.w+=__shfl_xor(tvb.w,m);
  }
  int wv = t >> 6;
  if ((t & 56) == 0){
    *(v4*)&sP[wv][i0] = sva; *(v4*)&sP[wv][i0+4] = svb;
    *(v4*)&tP[wv][i0] = tva; *(v4*)&tP[wv][i0+4] = tvb;
  }
  __syncthreads();
  if (t < 64){
    sArr[(size_t)bh*N_ + n0 + t] = sP[0][t]+sP[1][t]+sP[2][t]+sP[3][t];
    tArr[(size_t)bh*N_ + n0 + t] = tP[0][t]+tP[1][t]+tP[2][t]+tP[3][t];
  }
}

// ---------------- Kernel 3: MFMA masked-softmax + split-bf16 PV ----------------
__global__ void __launch_bounds__(256) attn_kernel(
    const unsigned* __restrict__ maskT,   // [b][64][N]
    const short* __restrict__ WhT_hi,     // [bh][f][n]
    const short* __restrict__ WhT_lo,
    const float* __restrict__ sArr,
    const float* __restrict__ tArr,
    float* __restrict__ hpWS)             // [bh][n][f]
{
  int v = blockIdx.x;           // 512 blocks, XCD swizzle
  int seq = v >> 3, x8 = v & 7;
  int bh = (seq >> 5)*8 + x8;
  int itile = seq & 31;
  int b = bh >> 2;
  int n0 = itile * 64;
  int t = threadIdx.x;
  int l = t & 63, w = t >> 6;
  int ihalf = w & 1, fhalf = w >> 1;
  int lg = l >> 5, ln = l & 31;

  __shared__ float tvecL[N_];
  __shared__ short whHiL[128*40];   // [f 0..127][j 0..31], stride 40 shorts (80B)
  __shared__ short whLoL[128*40];
  __shared__ float mxPart[4][64];
  __shared__ float mxL[64];
  __shared__ float amL[64];
  __shared__ float lsL[64];

  const float* tp = tArr + (size_t)bh*N_;
  #pragma unroll
  for (int q=0;q<8;q++) tvecL[t + q*256] = tp[t + q*256];

  // staging registers + helpers
  s16x8 rh0, rh1, rl0, rl1;
  int srow = t >> 2, sseg = t & 3;
  const short* gHi = WhT_hi + (size_t)bh*F_*N_;
  const short* gLo = WhT_lo + (size_t)bh*F_*N_;
  auto STAGE = [&](int jj0){
    size_t o = (size_t)srow*N_ + jj0 + sseg*8;
    rh0 = *(const s16x8*)(gHi + o);
    rh1 = *(const s16x8*)(gHi + o + (size_t)64*N_);
    rl0 = *(const s16x8*)(gLo + o);
    rl1 = *(const s16x8*)(gLo + o + (size_t)64*N_);
  };
  auto WRITE = [&](){
    int wo = srow*40 + sseg*8;
    *(s16x4*)&whHiL[wo]          = __builtin_shufflevector(rh0,rh0,0,1,2,3);
    *(s16x4*)&whHiL[wo+4]        = __builtin_shufflevector(rh0,rh0,4,5,6,7);
    *(s16x4*)&whHiL[wo+64*40]    = __builtin_shufflevector(rh1,rh1,0,1,2,3);
    *(s16x4*)&whHiL[wo+64*40+4]  = __builtin_shufflevector(rh1,rh1,4,5,6,7);
    *(s16x4*)&whLoL[wo]          = __builtin_shufflevector(rl0,rl0,0,1,2,3);
    *(s16x4*)&whLoL[wo+4]        = __builtin_shufflevector(rl0,rl0,4,5,6,7);
    *(s16x4*)&whLoL[wo+64*40]    = __builtin_shufflevector(rl1,rl1,0,1,2,3);
    *(s16x4*)&whLoL[wo+64*40+4]  = __builtin_shufflevector(rl1,rl1,4,5,6,7);
  };

  STAGE(0);
  int il = t & 63, qq = t >> 6;
  float s_il = sArr[(size_t)bh*N_ + n0 + il];
  __syncthreads();   // tvecL ready

  // phase 1: per-row max over active j
  float mx = NEG_BIG_F;
  const unsigned* mb1p = maskT + (size_t)b*64*N_ + n0;
  for (int wq=0; wq<16; wq++){
    int wdi = qq + wq*4;
    unsigned wd = mb1p[(size_t)wdi*N_ + il];
    while (wd){
      int k2 = __builtin_ctz(wd); wd &= wd - 1;
      float e = s_il + tvecL[wdi*32 + k2];
      e = fmaxf(e, 0.2f*e);
      mx = fmaxf(mx, e);
    }
  }
  mxPart[qq][il] = mx;
  WRITE();           // publish tile 0 (no one reads until next barrier)
  __syncthreads();
  if (t < 64){
    float m = fmaxf(fmaxf(mxPart[0][t], mxPart[1][t]), fmaxf(mxPart[2][t], mxPart[3][t]));
    amL[t] = (m <= -8.0e15f) ? 1.0f : 0.0f;
    mxL[t] = m;
  }
  __syncthreads();

  // lane constants
  int irow = n0 + ihalf*32 + ln;
  float s_lane  = sArr[(size_t)bh*N_ + irow];
  float mx_lane = mxL[ihalf*32 + ln];
  float am_lane = amL[ihalf*32 + ln];
  const unsigned* mrow = maskT + (size_t)b*64*N_ + irow;

  f32x16 acc0, acc1;
  #pragma unroll
  for (int e2=0;e2<16;e2++){ acc0[e2]=0.f; acc1[e2]=0.f; }
  float lsum = 0.f;

  unsigned mword = mrow[0];
  for (int c=0;c<64;c++){
    int j0 = c*32;
    unsigned mword_nx = (c<63) ? mrow[(size_t)(c+1)*N_] : 0u;
    if (c<63) STAGE(j0 + 32);
    #pragma unroll
    for (int ks=0; ks<2; ks++){
      int sh0 = ks*16 + lg*8;
      int jb = j0 + sh0;
      v4 ta = *(const v4*)&tvecL[jb];
      v4 tb = *(const v4*)&tvecL[jb+4];
      s16x8 ahi, alo;
      #pragma unroll
      for (int e=0;e<8;e++){
        float tv = (e<4) ? ta[e] : tb[e-4];
        float ev = s_lane + tv;
        ev = fmaxf(ev, 0.2f*ev);
        float pe = ((mword >> (sh0+e)) & 1u) ? __expf(ev - mx_lane) : am_lane;
        lsum += pe;
        short hb2 = bfbits(pe);
        ahi[e] = hb2;
        alo[e] = bfbits(pe - bfback(hb2));
      }
      int off0 = (fhalf*64 + ln)*40 + sh0;
      s16x4 h0 = *(const s16x4*)&whHiL[off0];
      s16x4 h1 = *(const s16x4*)&whHiL[off0+4];
      s16x4 q0 = *(const s16x4*)&whLoL[off0];
      s16x4 q1 = *(const s16x4*)&whLoL[off0+4];
      s16x8 bhi = __builtin_shufflevector(h0,h1,0,1,2,3,4,5,6,7);
      s16x8 blo = __builtin_shufflevector(q0,q1,0,1,2,3,4,5,6,7);
      acc0 = __builtin_amdgcn_mfma_f32_32x32x16_bf16(ahi, bhi, acc0, 0,0,0);
      acc0 = __builtin_amdgcn_mfma_f32_32x32x16_bf16(ahi, blo, acc0, 0,0,0);
      acc0 = __builtin_amdgcn_mfma_f32_32x32x16_bf16(alo, bhi, acc0, 0,0,0);
      int off1 = off0 + 32*40;
      s16x4 h2 = *(const s16x4*)&whHiL[off1];
      s16x4 h3 = *(const s16x4*)&whHiL[off1+4];
      s16x4 q2 = *(const s16x4*)&whLoL[off1];
      s16x4 q3 = *(const s16x4*)&whLoL[off1+4];
      s16x8 bhi1 = __builtin_shufflevector(h2,h3,0,1,2,3,4,5,6,7);
      s16x8 blo1 = __builtin_shufflevector(q2,q3,0,1,2,3,4,5,6,7);
      acc1 = __builtin_amdgcn_mfma_f32_32x32x16_bf16(ahi, bhi1, acc1, 0,0,0);
      acc1 = __builtin_amdgcn_mfma_f32_32x32x16_bf16(ahi, blo1, acc1, 0,0,0);
      acc1 = __builtin_amdgcn_mfma_f32_32x32x16_bf16(alo, bhi1, acc1, 0,0,0);
    }
    __syncthreads();
    if (c<63) WRITE();
    __syncthreads();
    mword = mword_nx;
  }

  // epilogue: normalize + elu + store
  lsum += __shfl_xor(lsum, 32);
  if (w < 2 && lg == 0) lsL[ihalf*32 + ln] = 1.0f / lsum;
  __syncthreads();
  float* hpb = hpWS + ((size_t)bh*N_ + n0 + ihalf*32)*F_ + fhalf*64 + ln;
  #pragma unroll
  for (int q4=0;q4<4;q4++){
    v4 inv4 = *(const v4*)&lsL[ihalf*32 + q4*8 + lg*4];
    #pragma unroll
    for (int rr=0;rr<4;rr++){
      int r = q4*4+rr;
      int irl = rr + 8*q4 + 4*lg;
      float v0 = acc0[r]*inv4[rr];
      v0 = v0 > 0.f ? v0 : expm1f(v0);
      hpb[(size_t)irl*F_] = v0;
      float v1 = acc1[r]*inv4[rr];
      v1 = v1 > 0.f ? v1 : expm1f(v1);
      hpb[(size_t)irl*F_ + 32] = v1;
    }
  }
}

// ---------------- Kernel 4: projection ----------------
__global__ void __launch_bounds__(256) proj_kernel(
    const float* __restrict__ hpWS,
    const float* __restrict__ pw_l,
    const float* __restrict__ pb_l,
    float* __restrict__ h_out)
{
  int v = blockIdx.x;
  int b = v >> 6;
  int n0 = (v & 63) * 32;
  int t = threadIdx.x;
  int fi = t & 31, ig = t >> 5;
  int f0 = fi*4, i0 = ig*4;

  __shared__ float hpT[128][40];
  v4 acc[4];
  v4 bias = *(const v4*)(pb_l + f0);
  #pragma unroll
  for (int r=0;r<4;r++) acc[r] = bias;

  for (int kh=0; kh<H_; kh++){
    __syncthreads();
    for (int idx = t; idx < 32*128; idx += 256){
      int i = idx >> 7, kf = idx & 127;
      hpT[kf][i] = hpWS[((size_t)(b*H_+kh)*N_ + n0 + i)*F_ + kf];
    }
    __syncthreads();
    const float* pwk = pw_l + (size_t)kh*F_*F_;
    for (int kf=0;kf<F_;kf++){
      v4 w = *(const v4*)(pwk + (size_t)kf*F_ + f0);
      v4 pa = *(const v4*)&hpT[kf][i0];
      acc[0] += pa.x*w; acc[1] += pa.y*w; acc[2] += pa.z*w; acc[3] += pa.w*w;
    }
  }
  #pragma unroll
  for (int r=0;r<4;r++)
    *(v4*)(h_out + (size_t)(b*N_ + n0 + i0 + r)*F_ + f0) = acc[r];
}

// ---------------- Kernel 5: output head ----------------
__global__ void __launch_bounds__(256) out_kernel(
    const float* __restrict__ h,
    const float* __restrict__ deltas,
    const float* __restrict__ alpha,
    const float* __restrict__ beta,
    const float* __restrict__ ow1, const float* __restrict__ ob1,
    const float* __restrict__ ow2, const float* __restrict__ ob2,
    float* __restrict__ out)
{
  int row0 = blockIdx.x * 32;
  int t = threadIdx.x;
  int il = t >> 3, fg = t & 7;
  int f0 = fg * 8;
  __shared__ float hL[32][132];
  for (int idx = t; idx < 32*128; idx += 256){
    int i = idx >> 7, k = idx & 127;
    hL[i][k] = h[(size_t)(row0+i)*F_ + k];
  }
  __syncthreads();
  float acc[8];
  #pragma unroll
  for (int q=0;q<8;q++) acc[q] = ob1[f0+q];
  for (int k=0;k<F_;k++){
    float c = hL[il][k];
    const float* w = ow1 + (size_t)k*64 + f0;
    v4 wa = *(const v4*)w; v4 wb = *(const v4*)(w+4);
    acc[0]+=c*wa.x; acc[1]+=c*wa.y; acc[2]+=c*wa.z; acc[3]+=c*wa.w;
    acc[4]+=c*wb.x; acc[5]+=c*wb.y; acc[6]+=c*wb.z; acc[7]+=c*wb.w;
  }
  float pp = 0.f;
  #pragma unroll
  for (int q=0;q<8;q++) pp += gelu_f(acc[q]) * ow2[f0+q];
  pp += __shfl_xor(pp, 1);
  pp += __shfl_xor(pp, 2);
  pp += __shfl_xor(pp, 4);
  if (fg == 0){
    int row = row0 + il;
    int n = row & (N_-1);
    float prop = pp + ob2[0];
    out[row] = sigmoid_f(alpha[n]) * deltas[row] + beta[0]*prop;
  }
}

extern "C" void kernel_launch(void* const* d_in, const int* in_sizes, int n_in,
                              void* d_out, int out_size, void* d_ws, size_t ws_size,
                              hipStream_t stream) {
  const float* deltas = (const float*)d_in[0];
  const float* evt    = (const float*)d_in[1];
  const float* adj    = (const float*)d_in[2];
  const float* mw1 = (const float*)d_in[3];
  const float* mb1 = (const float*)d_in[4];
  const float* mw2 = (const float*)d_in[5];
  const float* mb2 = (const float*)d_in[6];
  const float* mw3 = (const float*)d_in[7];
  const float* mb3 = (const float*)d_in[8];
  const float* gw1 = (const float*)d_in[9];
  const float* gb1 = (const float*)d_in[10];
  const float* gw2 = (const float*)d_in[11];
  const float* gb2 = (const float*)d_in[12];
  const float* Wg  = (const float*)d_in[13];
  const float* a_src = (const float*)d_in[14];
  const float* a_dst = (const float*)d_in[15];
  const float* pw = (const float*)d_in[16];
  const float* pb = (const float*)d_in[17];
  const float* ow1 = (const float*)d_in[18];
  const float* ob1 = (const float*)d_in[19];
  const float* ow2 = (const float*)d_in[20];
  const float* ob2 = (const float*)d_in[21];
  const float* alpha = (const float*)d_in[22];
  const float* beta  = (const float*)d_in[23];
  float* out = (float*)d_out;

  float* ws = (float*)d_ws;
  float* hA = ws;                                   // B*N*F
  float* hB = hA + (size_t)B_*N_*F_;                // B*N*F
  short* WhT_hi = (short*)(hB + (size_t)B_*N_*F_);  // 16*128*2048 shorts
  short* WhT_lo = WhT_hi + (size_t)B_*H_*F_*N_;
  float* hp = (float*)(WhT_lo + (size_t)B_*H_*F_*N_);   // B*H*N*F
  float* sA = hp + (size_t)B_*H_*N_*F_;
  float* tA = sA + (size_t)B_*H_*N_;
  unsigned* maskT = (unsigned*)(tA + (size_t)B_*H_*N_); // B*64*N words
  float* s1ws = hp;   // dead until first attn

  int BN = B_*N_;
  mask_kernel<<<B_*64, 256, 0, stream>>>(adj, maskT);
  mlp1_kernel<<<BN/16, 256, 0, stream>>>(deltas, evt, mw1, mb1, gw1, gb1, s1ws);
  mlp2_kernel<<<BN/16, 256, 0, stream>>>(s1ws, mw2, mb2, mw3, mb3, gw2, gb2, hA);
  const float* hin = hA; float* hout = hB;
  for (int l=0;l<2;l++){
    wh_kernel<<<16*32, 256, 0, stream>>>(hin,
        Wg + (size_t)l*H_*F_*F_, a_src + (size_t)l*H_*F_, a_dst + (size_t)l*H_*F_,
        WhT_hi, WhT_lo, sA, tA);
    attn_kernel<<<512, 256, 0, stream>>>(maskT, WhT_hi, WhT_lo, sA, tA, hp);
    proj_kernel<<<256, 256, 0, stream>>>(hp,
        pw + (size_t)l*H_*F_*F_, pb + (size_t)l*F_, hout);
    float* tmp = (float*)hin; hin = hout; hout = tmp;
  }
  out_kernel<<<BN/32, 256, 0, stream>>>(hin, deltas, alpha, beta, ow1, ob1, ow2, ob2, out);
}